// Round 14
// baseline (232.024 us; speedup 1.0000x reference)
//
#include <hip/hip_runtime.h>

#define NN 100000
#define CH 64
#define CAP 64                 // bucket capacity; deg ~ Poisson(12), P(>=64) ~ 1e-30
#define NPART 8                // dst-range partitions (XCD count)
#define PSIZE ((NN + NPART - 1) / NPART)   // 12500
#define FILLB 640              // blocks per partition

__device__ __forceinline__ float bf_lo(unsigned u) { return __uint_as_float(u << 16); }
__device__ __forceinline__ float bf_hi(unsigned u) { return __uint_as_float(u & 0xffff0000u); }

// float -> bf16 bits, round-to-nearest-even (matches HW/NumPy)
__device__ __forceinline__ unsigned short f2bf(float f) {
    unsigned u = __float_as_uint(f);
    u += 0x7fffu + ((u >> 16) & 1u);
    return (unsigned short)(u >> 16);
}

// ---- bucket fill, dst-partitioned, int4-vectorized ----
__global__ __launch_bounds__(256) void k_fill(const int* __restrict__ src,
                                              const int* __restrict__ dst,
                                              unsigned* __restrict__ cnt,
                                              int* __restrict__ bsrc, int E) {
    int part = blockIdx.x & (NPART - 1);
    int blk  = blockIdx.x >> 3;
    int lo = part * PSIZE, hi = lo + PSIZE;
    int E4 = E >> 2;
    const int4* src4 = (const int4*)src;
    const int4* dst4 = (const int4*)dst;
    for (int i = blk * 256 + threadIdx.x; i < E4; i += FILLB * 256) {
        int4 d4 = dst4[i];
        int4 s4 = src4[i];
        if (d4.x >= lo && d4.x < hi) { unsigned p = atomicAdd(&cnt[d4.x], 1u); if (p < CAP) bsrc[(size_t)d4.x * CAP + p] = s4.x; }
        if (d4.y >= lo && d4.y < hi) { unsigned p = atomicAdd(&cnt[d4.y], 1u); if (p < CAP) bsrc[(size_t)d4.y * CAP + p] = s4.y; }
        if (d4.z >= lo && d4.z < hi) { unsigned p = atomicAdd(&cnt[d4.z], 1u); if (p < CAP) bsrc[(size_t)d4.z * CAP + p] = s4.z; }
        if (d4.w >= lo && d4.w < hi) { unsigned p = atomicAdd(&cnt[d4.w], 1u); if (p < CAP) bsrc[(size_t)d4.w * CAP + p] = s4.w; }
    }
    // tail (E not multiple of 4): part 0, first block only
    if (part == 0 && blk == 0) {
        for (int e = E4 * 4 + threadIdx.x; e < E; e += 256) {
            int d = dst[e];
            int s = src[e];
            unsigned p = atomicAdd(&cnt[d], 1u);
            if (p < CAP) bsrc[(size_t)d * CAP + p] = s;
        }
    }
}

// ---- prep: xb = bf16(x); dinv = rsqrt(cnt+1) ----
__global__ __launch_bounds__(256) void k_prep(const float* __restrict__ x,
                                              unsigned short* __restrict__ xb,
                                              const unsigned* __restrict__ cnt,
                                              float* __restrict__ dinv, int N) {
    int i = blockIdx.x * blockDim.x + threadIdx.x;
    int tot4 = N * CH / 4;
    if (i < tot4) {
        float4 v = ((const float4*)x)[i];
        ushort4 o;
        o.x = f2bf(v.x); o.y = f2bf(v.y); o.z = f2bf(v.z); o.w = f2bf(v.w);
        ((ushort4*)xb)[i] = o;
    }
    if (i < N) dinv[i] = rsqrtf((float)cnt[i] + 1.0f);
}

// ---- fused: pull-aggregate (bf16 gather) -> GEMM(Wg) -> relu+residual -> MLP -> out ----
// Weights/biases read from GLOBAL (L1-resident: Wg 16KB, W1 8KB, W2 4KB, all
// broadcast-read by every block) -> LDS only holds activations: 25 KB -> 6 blocks/CU.
__global__ __launch_bounds__(256) void k_at(
        const unsigned* __restrict__ cnt, const int* __restrict__ bsrc,
        const float* __restrict__ dinv, const float* __restrict__ x,
        const unsigned short* __restrict__ xb,
        const float* __restrict__ Wg, const float* __restrict__ bgcn,
        const float* __restrict__ W1, const float* __restrict__ b1,
        const float* __restrict__ W2, const float* __restrict__ b2,
        const float* __restrict__ W3, const float* __restrict__ b3,
        float* __restrict__ out, int N) {
    __shared__ float R2[64 * 65];   // agg tile -> vbuf -> h4   (16.6 KB)
    __shared__ float R3[64 * 33];   // h3                        (8.4 KB)
    int t = threadIdx.x;
    int nbase = blockIdx.x * 64;

    // ---- agg phase: thread = (node nl=t>>2, quad q=t&3 -> 16 channels) ----
    {
        int nl = t >> 2, q = t & 3;
        int n = nbase + nl;
        float* r2p = R2 + nl * 65 + q * 16;
        if (n < N) {
            int c = (int)cnt[n]; if (c > CAP) c = CAP;
            const int* bp = bsrc + (size_t)n * CAP;
            float dn = dinv[n];
            float acc[16];
#pragma unroll
            for (int j = 0; j < 16; ++j) acc[j] = 0.f;
#pragma unroll 2
            for (int e = 0; e < c; ++e) {
                int s = bp[e];
                float w = dinv[s];
                const uint4* xp = (const uint4*)(xb + (size_t)s * CH) + q * 2;
                uint4 A = xp[0], B = xp[1];
                acc[0]  += bf_lo(A.x) * w; acc[1]  += bf_hi(A.x) * w;
                acc[2]  += bf_lo(A.y) * w; acc[3]  += bf_hi(A.y) * w;
                acc[4]  += bf_lo(A.z) * w; acc[5]  += bf_hi(A.z) * w;
                acc[6]  += bf_lo(A.w) * w; acc[7]  += bf_hi(A.w) * w;
                acc[8]  += bf_lo(B.x) * w; acc[9]  += bf_hi(B.x) * w;
                acc[10] += bf_lo(B.y) * w; acc[11] += bf_hi(B.y) * w;
                acc[12] += bf_lo(B.z) * w; acc[13] += bf_hi(B.z) * w;
                acc[14] += bf_lo(B.w) * w; acc[15] += bf_hi(B.w) * w;
            }
            // self-loop in fp32
            const float4* xq = (const float4*)(x + (size_t)n * CH) + q * 4;
            float4 u0 = xq[0], u1 = xq[1], u2 = xq[2], u3 = xq[3];
            r2p[0]  = dn * (acc[0]  + u0.x * dn); r2p[1]  = dn * (acc[1]  + u0.y * dn);
            r2p[2]  = dn * (acc[2]  + u0.z * dn); r2p[3]  = dn * (acc[3]  + u0.w * dn);
            r2p[4]  = dn * (acc[4]  + u1.x * dn); r2p[5]  = dn * (acc[5]  + u1.y * dn);
            r2p[6]  = dn * (acc[6]  + u1.z * dn); r2p[7]  = dn * (acc[7]  + u1.w * dn);
            r2p[8]  = dn * (acc[8]  + u2.x * dn); r2p[9]  = dn * (acc[9]  + u2.y * dn);
            r2p[10] = dn * (acc[10] + u2.z * dn); r2p[11] = dn * (acc[11] + u2.w * dn);
            r2p[12] = dn * (acc[12] + u3.x * dn); r2p[13] = dn * (acc[13] + u3.y * dn);
            r2p[14] = dn * (acc[14] + u3.z * dn); r2p[15] = dn * (acc[15] + u3.w * dn);
        } else {
#pragma unroll
            for (int j = 0; j < 16; ++j) r2p[j] = 0.f;
        }
    }
    __syncthreads();

    // ---- phase A: gcn = act @ Wg, register-blocked 4 cols x 4 nodes ----
    // Wg row k is 16 float4s; this thread needs float4 #cg of each row (L1-hot).
    int cg = t & 15, ng = t >> 4;
    float accv[4][4];
#pragma unroll
    for (int i = 0; i < 4; ++i)
#pragma unroll
        for (int u = 0; u < 4; ++u) accv[i][u] = 0.f;
    const float4* Wg4 = (const float4*)Wg;
#pragma unroll 4
    for (int k = 0; k < 64; ++k) {
        float4 wv = Wg4[k * 16 + cg];
        float va = R2[(ng * 4 + 0) * 65 + k];   // 16-lane broadcast
        float vb = R2[(ng * 4 + 1) * 65 + k];
        float vc = R2[(ng * 4 + 2) * 65 + k];
        float vd = R2[(ng * 4 + 3) * 65 + k];
        accv[0][0] += va * wv.x; accv[0][1] += va * wv.y; accv[0][2] += va * wv.z; accv[0][3] += va * wv.w;
        accv[1][0] += vb * wv.x; accv[1][1] += vb * wv.y; accv[1][2] += vb * wv.z; accv[1][3] += vb * wv.w;
        accv[2][0] += vc * wv.x; accv[2][1] += vc * wv.y; accv[2][2] += vc * wv.z; accv[2][3] += vc * wv.w;
        accv[3][0] += vd * wv.x; accv[3][1] += vd * wv.y; accv[3][2] += vd * wv.z; accv[3][3] += vd * wv.w;
    }
    __syncthreads();

    // vbuf = relu(gcn + bg) + x -> R2
    float4 bgv = *((const float4*)bgcn + cg);
#pragma unroll
    for (int i = 0; i < 4; ++i) {
        int nl2 = ng * 4 + i;
        int gr = nbase + nl2;
        float4 xv = make_float4(0.f, 0.f, 0.f, 0.f);
        if (gr < N) xv = *((const float4*)(x + (size_t)gr * CH) + cg);
        float* rp = R2 + nl2 * 65 + cg * 4;
        rp[0] = fmaxf(accv[i][0] + bgv.x, 0.f) + xv.x;
        rp[1] = fmaxf(accv[i][1] + bgv.y, 0.f) + xv.y;
        rp[2] = fmaxf(accv[i][2] + bgv.z, 0.f) + xv.z;
        rp[3] = fmaxf(accv[i][3] + bgv.w, 0.f) + xv.w;
    }
    __syncthreads();

    // ---- phase 2: h3 (W1: 64->32). thread = (node nl, col-group g of 8) ----
    int nl = t & 63, g = t >> 6;
    const float4* W14 = (const float4*)W1;   // row k = 8 float4s
    {
        float a[8];
        float4 b1a = *((const float4*)b1 + 2 * g);
        float4 b1b = *((const float4*)b1 + 2 * g + 1);
        a[0] = b1a.x; a[1] = b1a.y; a[2] = b1a.z; a[3] = b1a.w;
        a[4] = b1b.x; a[5] = b1b.y; a[6] = b1b.z; a[7] = b1b.w;
#pragma unroll 4
        for (int k = 0; k < 64; ++k) {
            float v = R2[nl * 65 + k];
            float4 wA = W14[k * 8 + 2 * g];
            float4 wB = W14[k * 8 + 2 * g + 1];
            a[0] += v * wA.x; a[1] += v * wA.y; a[2] += v * wA.z; a[3] += v * wA.w;
            a[4] += v * wB.x; a[5] += v * wB.y; a[6] += v * wB.z; a[7] += v * wB.w;
        }
#pragma unroll
        for (int j = 0; j < 8; ++j) R3[nl * 33 + 8 * g + j] = a[j];
    }
    __syncthreads();

    // ---- phase 3: h4 (W2: 32->32) -> R2 (vbuf dead) ----
    const float4* W24 = (const float4*)W2;
    {
        float a[8];
        float4 b2a = *((const float4*)b2 + 2 * g);
        float4 b2b = *((const float4*)b2 + 2 * g + 1);
        a[0] = b2a.x; a[1] = b2a.y; a[2] = b2a.z; a[3] = b2a.w;
        a[4] = b2b.x; a[5] = b2b.y; a[6] = b2b.z; a[7] = b2b.w;
#pragma unroll 4
        for (int k = 0; k < 32; ++k) {
            float v = fmaxf(R3[nl * 33 + k], 0.0f);
            float4 wA = W24[k * 8 + 2 * g];
            float4 wB = W24[k * 8 + 2 * g + 1];
            a[0] += v * wA.x; a[1] += v * wA.y; a[2] += v * wA.z; a[3] += v * wA.w;
            a[4] += v * wB.x; a[5] += v * wB.y; a[6] += v * wB.z; a[7] += v * wB.w;
        }
#pragma unroll
        for (int j = 0; j < 8; ++j) R2[nl * 65 + 8 * g + j] = a[j];
    }
    __syncthreads();

    // ---- phase 4: out (W3: 32->2) ----
    if (t < 128) {
        int nl4 = t >> 1, g4 = t & 1;
        int gr = nbase + nl4;
        if (gr < N) {
            float y = b3[g4];
#pragma unroll
            for (int k = 0; k < 32; ++k)
                y += fmaxf(R2[nl4 * 65 + k], 0.0f) * W3[k * 2 + g4];
            out[(size_t)gr * 2 + g4] = y;
        }
    }
}

extern "C" void kernel_launch(void* const* d_in, const int* in_sizes, int n_in,
                              void* d_out, int out_size, void* d_ws, size_t ws_size,
                              hipStream_t stream) {
    const float* x  = (const float*)d_in[0];
    const int*   ei = (const int*)d_in[1];
    const float* Wg = (const float*)d_in[2];
    const float* bg = (const float*)d_in[3];
    const float* W1 = (const float*)d_in[4];
    const float* b1 = (const float*)d_in[5];
    const float* W2 = (const float*)d_in[6];
    const float* b2 = (const float*)d_in[7];
    const float* W3 = (const float*)d_in[8];
    const float* b3 = (const float*)d_in[9];
    float* out = (float*)d_out;

    const int N = NN;
    const int E = in_sizes[1] / 2;
    const int* src = ei;
    const int* dst = ei + E;

    // ws: cnt[N] dinv[N] bsrc[N*CAP] xb[N*CH bf16] = ~39 MB
    char* base = (char*)d_ws;
    size_t o = 0;
    auto alloc = [&](size_t bytes) { void* p = base + o; o = (o + bytes + 255) & ~(size_t)255; return p; };
    unsigned*       cnt  = (unsigned*)alloc((size_t)N * 4);
    float*          dinv = (float*)alloc((size_t)N * 4);
    int*            bsrc = (int*)alloc((size_t)N * CAP * 4);
    unsigned short* xb   = (unsigned short*)alloc((size_t)N * CH * 2);

    hipMemsetAsync(cnt, 0, (size_t)N * 4, stream);

    k_fill<<<NPART * FILLB, 256, 0, stream>>>(src, dst, cnt, bsrc, E);
    int prep_blocks = (N * CH / 4 + 255) / 256;
    k_prep<<<prep_blocks, 256, 0, stream>>>(x, xb, cnt, dinv, N);
    k_at<<<(N + 63) / 64, 256, 0, stream>>>(cnt, bsrc, dinv, x, xb, Wg, bg,
                                            W1, b1, W2, b2, W3, b3, out, N);
}

// Round 15
// 208.105 us; speedup vs baseline: 1.1149x; 1.1149x over previous
//
#include <hip/hip_runtime.h>

#define NN 100000
#define CH 64
#define CAP 64                 // bucket capacity; deg ~ Poisson(12), P(>=64) ~ 1e-30
#define NPART 8                // dst-range partitions (XCD count)
#define PSIZE ((NN + NPART - 1) / NPART)   // 12500
#define FILLB 640              // blocks per partition

__device__ __forceinline__ float bf_lo(unsigned u) { return __uint_as_float(u << 16); }
__device__ __forceinline__ float bf_hi(unsigned u) { return __uint_as_float(u & 0xffff0000u); }

// float -> bf16 bits, round-to-nearest-even (matches HW/NumPy)
__device__ __forceinline__ unsigned short f2bf(float f) {
    unsigned u = __float_as_uint(f);
    u += 0x7fffu + ((u >> 16) & 1u);
    return (unsigned short)(u >> 16);
}

// ---- bucket fill, dst-partitioned, int4-vectorized (unchanged from R12) ----
__global__ __launch_bounds__(256) void k_fill(const int* __restrict__ src,
                                              const int* __restrict__ dst,
                                              unsigned* __restrict__ cnt,
                                              int* __restrict__ bsrc, int E) {
    int part = blockIdx.x & (NPART - 1);
    int blk  = blockIdx.x >> 3;
    int lo = part * PSIZE, hi = lo + PSIZE;
    int E4 = E >> 2;
    const int4* src4 = (const int4*)src;
    const int4* dst4 = (const int4*)dst;
    for (int i = blk * 256 + threadIdx.x; i < E4; i += FILLB * 256) {
        int4 d4 = dst4[i];
        int4 s4 = src4[i];
        if (d4.x >= lo && d4.x < hi) { unsigned p = atomicAdd(&cnt[d4.x], 1u); if (p < CAP) bsrc[(size_t)d4.x * CAP + p] = s4.x; }
        if (d4.y >= lo && d4.y < hi) { unsigned p = atomicAdd(&cnt[d4.y], 1u); if (p < CAP) bsrc[(size_t)d4.y * CAP + p] = s4.y; }
        if (d4.z >= lo && d4.z < hi) { unsigned p = atomicAdd(&cnt[d4.z], 1u); if (p < CAP) bsrc[(size_t)d4.z * CAP + p] = s4.z; }
        if (d4.w >= lo && d4.w < hi) { unsigned p = atomicAdd(&cnt[d4.w], 1u); if (p < CAP) bsrc[(size_t)d4.w * CAP + p] = s4.w; }
    }
    if (part == 0 && blk == 0) {
        for (int e = E4 * 4 + threadIdx.x; e < E; e += 256) {
            int d = dst[e];
            int s = src[e];
            unsigned p = atomicAdd(&cnt[d], 1u);
            if (p < CAP) bsrc[(size_t)d * CAP + p] = s;
        }
    }
}

// ---- prep: xb = bf16(x); dinv = rsqrt(cnt+1) (unchanged from R12) ----
__global__ __launch_bounds__(256) void k_prep(const float* __restrict__ x,
                                              unsigned short* __restrict__ xb,
                                              const unsigned* __restrict__ cnt,
                                              float* __restrict__ dinv, int N) {
    int i = blockIdx.x * blockDim.x + threadIdx.x;
    int tot4 = N * CH / 4;
    if (i < tot4) {
        float4 v = ((const float4*)x)[i];
        ushort4 o;
        o.x = f2bf(v.x); o.y = f2bf(v.y); o.z = f2bf(v.z); o.w = f2bf(v.w);
        ((ushort4*)xb)[i] = o;
    }
    if (i < N) dinv[i] = rsqrtf((float)cnt[i] + 1.0f);
}

// ---- fused: agg (bf16 gather) -> GEMM(Wg) -> relu+residual -> MLP -> out ----
// 32-node tile, 256 thr. Weights in LDS (R12 tail structure), LDS ~29 KB -> 5 blocks/CU.
// agg: 8 threads/node (o=t&7), 8 channels each, 1 uint4 gather per edge.
__global__ __launch_bounds__(256) void k_at(
        const unsigned* __restrict__ cnt, const int* __restrict__ bsrc,
        const float* __restrict__ dinv, const float* __restrict__ x,
        const unsigned short* __restrict__ xb,
        const float* __restrict__ Wg, const float* __restrict__ bgcn,
        const float* __restrict__ W1, const float* __restrict__ b1,
        const float* __restrict__ W2, const float* __restrict__ b2,
        const float* __restrict__ W3, const float* __restrict__ b3,
        float* __restrict__ out, int N) {
    __shared__ float R1[4096];      // Wg; after phase A: W1(0)+W2(@2048)+W3(@3072)+b1@3136+b2@3168+b3@3200
    __shared__ float R2[32 * 65];   // agg tile -> vbuf -> h4   (8.32 KB)
    __shared__ float R3[32 * 33];   // h3                        (4.2 KB)
    __shared__ float bgs[64];
    int t = threadIdx.x;
    int nbase = blockIdx.x * 32;

    for (int i = t; i < 4096; i += 256) R1[i] = Wg[i];
    if (t < 64) bgs[t] = bgcn[t];

    // ---- agg: thread = (node nl=t>>3, oct o=t&7 -> 8 channels) ----
    {
        int nl = t >> 3, o = t & 7;
        int n = nbase + nl;
        float* r2p = R2 + nl * 65 + o * 8;
        if (n < N) {
            int c = (int)cnt[n]; if (c > CAP) c = CAP;
            const int* bp = bsrc + (size_t)n * CAP;
            float dn = dinv[n];
            float acc[8];
#pragma unroll
            for (int j = 0; j < 8; ++j) acc[j] = 0.f;
#pragma unroll 4
            for (int e = 0; e < c; ++e) {
                int s = bp[e];
                float w = dinv[s];
                uint4 A = ((const uint4*)(xb + (size_t)s * CH))[o];
                acc[0] += bf_lo(A.x) * w; acc[1] += bf_hi(A.x) * w;
                acc[2] += bf_lo(A.y) * w; acc[3] += bf_hi(A.y) * w;
                acc[4] += bf_lo(A.z) * w; acc[5] += bf_hi(A.z) * w;
                acc[6] += bf_lo(A.w) * w; acc[7] += bf_hi(A.w) * w;
            }
            // self-loop in fp32
            const float4* xq = (const float4*)(x + (size_t)n * CH);
            float4 u0 = xq[2 * o], u1 = xq[2 * o + 1];
            r2p[0] = dn * (acc[0] + u0.x * dn); r2p[1] = dn * (acc[1] + u0.y * dn);
            r2p[2] = dn * (acc[2] + u0.z * dn); r2p[3] = dn * (acc[3] + u0.w * dn);
            r2p[4] = dn * (acc[4] + u1.x * dn); r2p[5] = dn * (acc[5] + u1.y * dn);
            r2p[6] = dn * (acc[6] + u1.z * dn); r2p[7] = dn * (acc[7] + u1.w * dn);
        } else {
#pragma unroll
            for (int j = 0; j < 8; ++j) r2p[j] = 0.f;
        }
    }
    __syncthreads();

    // ---- phase A: gcn = act @ Wg. thread = (cg=t&15 -> 4 cols, ng=t>>4 -> 2 nodes) ----
    int cg = t & 15, ng = t >> 4;
    float accv[2][4];
#pragma unroll
    for (int i = 0; i < 2; ++i)
#pragma unroll
        for (int u = 0; u < 4; ++u) accv[i][u] = 0.f;
#pragma unroll 4
    for (int k = 0; k < 64; ++k) {
        float wv0 = R1[k * 64 + cg * 4 + 0];
        float wv1 = R1[k * 64 + cg * 4 + 1];
        float wv2 = R1[k * 64 + cg * 4 + 2];
        float wv3 = R1[k * 64 + cg * 4 + 3];
        float va = R2[(ng * 2 + 0) * 65 + k];   // 16-lane broadcast
        float vb = R2[(ng * 2 + 1) * 65 + k];
        accv[0][0] += va * wv0; accv[0][1] += va * wv1; accv[0][2] += va * wv2; accv[0][3] += va * wv3;
        accv[1][0] += vb * wv0; accv[1][1] += vb * wv1; accv[1][2] += vb * wv2; accv[1][3] += vb * wv3;
    }
    __syncthreads();

    // reload R1 with MLP weights; vbuf = relu(gcn + bg) + x -> R2
    for (int i = t; i < 2048; i += 256) R1[i] = W1[i];
    for (int i = t; i < 1024; i += 256) R1[2048 + i] = W2[i];
    if (t < 64) R1[3072 + t] = W3[t];
    if (t < 32) { R1[3136 + t] = b1[t]; R1[3168 + t] = b2[t]; }
    if (t < 2) R1[3200 + t] = b3[t];
#pragma unroll
    for (int i = 0; i < 2; ++i) {
        int nl2 = ng * 2 + i;
        int gr = nbase + nl2;
        float4 xv = make_float4(0.f, 0.f, 0.f, 0.f);
        if (gr < N) xv = *((const float4*)(x + (size_t)gr * CH) + cg);
        float* rp = R2 + nl2 * 65 + cg * 4;
        rp[0] = fmaxf(accv[i][0] + bgs[cg * 4 + 0], 0.f) + xv.x;
        rp[1] = fmaxf(accv[i][1] + bgs[cg * 4 + 1], 0.f) + xv.y;
        rp[2] = fmaxf(accv[i][2] + bgs[cg * 4 + 2], 0.f) + xv.z;
        rp[3] = fmaxf(accv[i][3] + bgs[cg * 4 + 3], 0.f) + xv.w;
    }
    __syncthreads();

    // ---- phase 2: h3 (W1: 64->32). thread = (node nl=t&31, g2=t>>5 -> 4 cols) ----
    int nl = t & 31, g2 = t >> 5;
    {
        float a[4];
#pragma unroll
        for (int j = 0; j < 4; ++j) a[j] = R1[3136 + 4 * g2 + j];
#pragma unroll 4
        for (int k = 0; k < 64; ++k) {
            float v = R2[nl * 65 + k];
#pragma unroll
            for (int j = 0; j < 4; ++j)
                a[j] += v * R1[k * 32 + 4 * g2 + j];
        }
#pragma unroll
        for (int j = 0; j < 4; ++j) R3[nl * 33 + 4 * g2 + j] = a[j];
    }
    __syncthreads();

    // ---- phase 3: h4 (W2: 32->32) -> R2 (vbuf dead) ----
    {
        float a[4];
#pragma unroll
        for (int j = 0; j < 4; ++j) a[j] = R1[3168 + 4 * g2 + j];
#pragma unroll 4
        for (int k = 0; k < 32; ++k) {
            float v = fmaxf(R3[nl * 33 + k], 0.0f);
#pragma unroll
            for (int j = 0; j < 4; ++j)
                a[j] += v * R1[2048 + k * 32 + 4 * g2 + j];
        }
#pragma unroll
        for (int j = 0; j < 4; ++j) R2[nl * 65 + 4 * g2 + j] = a[j];
    }
    __syncthreads();

    // ---- phase 4: out (W3: 32->2) ----
    if (t < 64) {
        int nl4 = t >> 1, g4 = t & 1;
        int gr = nbase + nl4;
        if (gr < N) {
            float y = R1[3200 + g4];
#pragma unroll
            for (int k = 0; k < 32; ++k)
                y += fmaxf(R2[nl4 * 65 + k], 0.0f) * R1[3072 + k * 2 + g4];
            out[(size_t)gr * 2 + g4] = y;
        }
    }
}

extern "C" void kernel_launch(void* const* d_in, const int* in_sizes, int n_in,
                              void* d_out, int out_size, void* d_ws, size_t ws_size,
                              hipStream_t stream) {
    const float* x  = (const float*)d_in[0];
    const int*   ei = (const int*)d_in[1];
    const float* Wg = (const float*)d_in[2];
    const float* bg = (const float*)d_in[3];
    const float* W1 = (const float*)d_in[4];
    const float* b1 = (const float*)d_in[5];
    const float* W2 = (const float*)d_in[6];
    const float* b2 = (const float*)d_in[7];
    const float* W3 = (const float*)d_in[8];
    const float* b3 = (const float*)d_in[9];
    float* out = (float*)d_out;

    const int N = NN;
    const int E = in_sizes[1] / 2;
    const int* src = ei;
    const int* dst = ei + E;

    // ws: cnt[N] dinv[N] bsrc[N*CAP] xb[N*CH bf16] = ~39 MB
    char* base = (char*)d_ws;
    size_t o = 0;
    auto alloc = [&](size_t bytes) { void* p = base + o; o = (o + bytes + 255) & ~(size_t)255; return p; };
    unsigned*       cnt  = (unsigned*)alloc((size_t)N * 4);
    float*          dinv = (float*)alloc((size_t)N * 4);
    int*            bsrc = (int*)alloc((size_t)N * CAP * 4);
    unsigned short* xb   = (unsigned short*)alloc((size_t)N * CH * 2);

    hipMemsetAsync(cnt, 0, (size_t)N * 4, stream);

    k_fill<<<NPART * FILLB, 256, 0, stream>>>(src, dst, cnt, bsrc, E);
    int prep_blocks = (N * CH / 4 + 255) / 256;
    k_prep<<<prep_blocks, 256, 0, stream>>>(x, xb, cnt, dinv, N);
    k_at<<<(N + 31) / 32, 256, 0, stream>>>(cnt, bsrc, dinv, x, xb, Wg, bg,
                                            W1, b1, W2, b2, W3, b3, out, N);
}